// Round 3
// baseline (120.361 us; speedup 1.0000x reference)
//
#include <hip/hip_runtime.h>
#include <hip/hip_bf16.h>
#include <stdint.h>

#define BATCH 16
#define NDIM  2048
#define MDIM  2048
#define DDIM  128   // LD == RD == 128

using bf16x8 = __attribute__((ext_vector_type(8))) short;
using bf16x4 = __attribute__((ext_vector_type(4))) short;  // 8 B
using f32x4  = __attribute__((ext_vector_type(4))) float;

__device__ __forceinline__ unsigned short f2bf(float f) {
    unsigned u = __float_as_uint(f);
    u += 0x7fffu + ((u >> 16) & 1u);   // round-to-nearest-even
    return (unsigned short)(u >> 16);
}

// ---------------------------------------------------------------------------
// Stage a 128x128 f32 tile (row stride 128 floats) into LDS as bf16 with the
// XOR-16B-chunk swizzle: logical chunk (row, ks) lands at byte
//   row*256 + (ks ^ (row & 15)) * 16.
// Per thread per iter: 32 B f32 load -> 8 bf16 -> one ds_write_b128.
// ---------------------------------------------------------------------------
__device__ __forceinline__ void stage_f32_tile(const float* __restrict__ g,
                                               char* lds, int t) {
    #pragma unroll
    for (int it = 0; it < 8; ++it) {
        const int idx = it * 256 + t;           // 16B-bf16-chunk index
        const int row = idx >> 4, ks = idx & 15;
        const float4* p = (const float4*)(g + row * 128 + ks * 8);
        float4 v0 = p[0], v1 = p[1];
        bf16x8 r;
        r[0] = f2bf(v0.x); r[1] = f2bf(v0.y); r[2] = f2bf(v0.z); r[3] = f2bf(v0.w);
        r[4] = f2bf(v1.x); r[5] = f2bf(v1.y); r[6] = f2bf(v1.z); r[7] = f2bf(v1.w);
        *(bf16x8*)(lds + row * 256 + ((ks ^ (row & 15)) * 16)) = r;
    }
}

// ---------------------------------------------------------------------------
// Fused kernel. Per block (bx=m-tile, by=n-tile, bz=batch):
//   phase 1: cw[m][i] = sum_j crit[m][j] * W[i][j]       (recomputed per block)
//            via mfma(A=W rows(i), B=crit rows(m)) -> lane holds cw[m][i0..i0+3]
//            -> packed bf16x4 ds_write_b64 into LDS as the phase-2 A-tile.
//   phase 2: out[n][m] = sum_i data[n][i] * cw[m][i]
//            via mfma(A=cw rows(m), B=data rows(n)) -> lane holds out[n][m0..m0+3]
//            -> one float4 global store per (x,y).
// LDS reuse: @0 = W then cw; @32768 = crit then data. Barriers between phases.
// ---------------------------------------------------------------------------
extern "C" __global__ __launch_bounds__(256)
void bd_fused_kernel(const float* __restrict__ data,
                     const float* __restrict__ crit,
                     const float* __restrict__ W,
                     float* __restrict__ out) {
    __shared__ __align__(16) char smem[65536];
    const int t    = threadIdx.x;
    const int lane = t & 63;
    const int w    = t >> 6;
    const int wr = w >> 1, wc = w & 1;
    const int lrow = lane & 15;
    const int lk   = lane >> 4;
    const int bx = blockIdx.x;  // m tile
    const int by = blockIdx.y;  // n tile
    const int bz = blockIdx.z;  // batch

    // ---- stage W (rows i) @0, crit tile (rows m) @32768 ----
    stage_f32_tile(W, smem, t);
    stage_f32_tile(crit + ((size_t)bz * MDIM + bx * 128) * DDIM, smem + 32768, t);
    __syncthreads();

    // ---- phase 1: acc1[x][y] = cw fragment, i = wr*64+x*16+lk*4+j, m = wc*64+y*16+lrow
    f32x4 acc1[4][4];
    #pragma unroll
    for (int x = 0; x < 4; ++x)
        #pragma unroll
        for (int y = 0; y < 4; ++y)
            acc1[x][y] = (f32x4){0.f, 0.f, 0.f, 0.f};

    #pragma unroll
    for (int ks = 0; ks < 4; ++ks) {
        const int ksl = ks * 4 + lk;
        bf16x8 a1[4], b1[4];
        #pragma unroll
        for (int x = 0; x < 4; ++x) {           // W rows (i)
            const int r = wr * 64 + x * 16 + lrow;
            a1[x] = *(const bf16x8*)(smem + r * 256 + ((ksl ^ (r & 15)) * 16));
        }
        #pragma unroll
        for (int y = 0; y < 4; ++y) {           // crit rows (m)
            const int r = wc * 64 + y * 16 + lrow;
            b1[y] = *(const bf16x8*)(smem + 32768 + r * 256 + ((ksl ^ (r & 15)) * 16));
        }
        #pragma unroll
        for (int x = 0; x < 4; ++x)
            #pragma unroll
            for (int y = 0; y < 4; ++y)
                acc1[x][y] = __builtin_amdgcn_mfma_f32_16x16x32_bf16(
                    a1[x], b1[y], acc1[x][y], 0, 0, 0);
    }
    __syncthreads();   // all reads of W/crit complete before overwrite

    // ---- write cw tile (bf16, swizzled) into @0 as phase-2 A-tile ----
    {
        const int m    = wc * 64 /*y added below*/;
        const int ks16 = wr * 8 + (lk >> 1);    // + x*2 below
        const int sub8 = (lk & 1) * 8;
        #pragma unroll
        for (int x = 0; x < 4; ++x)
            #pragma unroll
            for (int y = 0; y < 4; ++y) {
                const int row = m + y * 16 + lrow;
                const int ksx = ks16 + x * 2;
                bf16x4 v;
                v[0] = f2bf(acc1[x][y][0]);
                v[1] = f2bf(acc1[x][y][1]);
                v[2] = f2bf(acc1[x][y][2]);
                v[3] = f2bf(acc1[x][y][3]);
                *(bf16x4*)(smem + row * 256 + ((ksx ^ (row & 15)) * 16) + sub8) = v;
            }
    }
    // ---- stage data tile (rows n) @32768 ----
    stage_f32_tile(data + ((size_t)bz * NDIM + by * 128) * DDIM, smem + 32768, t);
    __syncthreads();

    // ---- phase 2: acc2[x][y], m = wr*64+x*16+lk*4+j, n = wc*64+y*16+lrow ----
    f32x4 acc2[4][4];
    #pragma unroll
    for (int x = 0; x < 4; ++x)
        #pragma unroll
        for (int y = 0; y < 4; ++y)
            acc2[x][y] = (f32x4){0.f, 0.f, 0.f, 0.f};

    #pragma unroll
    for (int ks = 0; ks < 4; ++ks) {
        const int ksl = ks * 4 + lk;
        bf16x8 a2[4], b2[4];
        #pragma unroll
        for (int x = 0; x < 4; ++x) {           // cw rows (m)
            const int r = wr * 64 + x * 16 + lrow;
            a2[x] = *(const bf16x8*)(smem + r * 256 + ((ksl ^ (r & 15)) * 16));
        }
        #pragma unroll
        for (int y = 0; y < 4; ++y) {           // data rows (n)
            const int r = wc * 64 + y * 16 + lrow;
            b2[y] = *(const bf16x8*)(smem + 32768 + r * 256 + ((ksl ^ (r & 15)) * 16));
        }
        #pragma unroll
        for (int x = 0; x < 4; ++x)
            #pragma unroll
            for (int y = 0; y < 4; ++y)
                acc2[x][y] = __builtin_amdgcn_mfma_f32_16x16x32_bf16(
                    a2[x], b2[y], acc2[x][y], 0, 0, 0);
    }

    // ---- epilogue: float4 stores, out[n][m0..m0+3] ----
    #pragma unroll
    for (int x = 0; x < 4; ++x)
        #pragma unroll
        for (int y = 0; y < 4; ++y) {
            const int n = wc * 64 + y * 16 + lrow;
            const int m = bx * 128 + wr * 64 + x * 16 + lk * 4;
            *(f32x4*)(out + ((size_t)bz * NDIM + by * 128 + n) * MDIM + m) = acc2[x][y];
        }
}

// ---------------------------------------------------------------------------
extern "C" void kernel_launch(void* const* d_in, const int* in_sizes, int n_in,
                              void* d_out, int out_size, void* d_ws, size_t ws_size,
                              hipStream_t stream) {
    const float* data = (const float*)d_in[0];  // [16,2048,128]
    const float* crit = (const float*)d_in[1];  // [16,2048,128]
    const float* W    = (const float*)d_in[2];  // [1,128,128]
    float* out = (float*)d_out;                 // [16,2048,2048]

    hipLaunchKernelGGL(bd_fused_kernel, dim3(16, 16, 16), dim3(256), 0, stream,
                       data, crit, W, out);
}

// Round 4
// 94.310 us; speedup vs baseline: 1.2762x; 1.2762x over previous
//
#include <hip/hip_runtime.h>
#include <hip/hip_bf16.h>
#include <stdint.h>

#define BATCH 16
#define NDIM  2048
#define MDIM  2048
#define DDIM  128   // LD == RD == 128

using bf16x8 = __attribute__((ext_vector_type(8))) short;
using bf16x4 = __attribute__((ext_vector_type(4))) short;  // 8 B
using f32x4  = __attribute__((ext_vector_type(4))) float;

__device__ __forceinline__ unsigned short f2bf(float f) {
    unsigned u = __float_as_uint(f);
    u += 0x7fffu + ((u >> 16) & 1u);   // round-to-nearest-even
    return (unsigned short)(u >> 16);
}

// ---------------------------------------------------------------------------
// Stage a 128x128 f32 tile (row stride 128 floats) into LDS as bf16 with the
// XOR-16B-chunk swizzle: logical chunk (row, ks) lands at byte
//   row*256 + (ks ^ (row & 15)) * 16.
// ---------------------------------------------------------------------------
__device__ __forceinline__ void stage_f32_tile(const float* __restrict__ g,
                                               char* lds, int t) {
    #pragma unroll
    for (int it = 0; it < 8; ++it) {
        const int idx = it * 256 + t;           // 16B-bf16-chunk index
        const int row = idx >> 4, ks = idx & 15;
        const float4* p = (const float4*)(g + row * 128 + ks * 8);
        float4 v0 = p[0], v1 = p[1];
        bf16x8 r;
        r[0] = f2bf(v0.x); r[1] = f2bf(v0.y); r[2] = f2bf(v0.z); r[3] = f2bf(v0.w);
        r[4] = f2bf(v1.x); r[5] = f2bf(v1.y); r[6] = f2bf(v1.z); r[7] = f2bf(v1.w);
        *(bf16x8*)(lds + row * 256 + ((ks ^ (row & 15)) * 16)) = r;
    }
}

// ---------------------------------------------------------------------------
// Fused persistent-tile kernel. Block (bx, bz, h):
//  - phase 1 (once): cw[m][i] = sum_j crit[bz, bx*128+m, j] * W[i][j]
//      staged W @0, crit @32768; mfma(W rows, crit rows); cw written back
//      bf16-swizzled to LDS @0 (the loop's A-tile). [R3-verified numerics]
//  - loop over 16 data tiles of 64 n-rows (rows h*1024 + tt*64 ..):
//      reg-prefetch next tile f32 -> cvt+ds_write dbuf @32768/@49152 ->
//      lgkmcnt(0) + raw s_barrier -> 8 MFMA -> 8 float4 stores.
//    One barrier per iteration; global loads stay in flight across it.
// ---------------------------------------------------------------------------
extern "C" __global__ __launch_bounds__(256, 2)
void bd_fused_kernel(const float* __restrict__ data,
                     const float* __restrict__ crit,
                     const float* __restrict__ W,
                     float* __restrict__ out) {
    __shared__ __align__(16) char smem[65536];
    const int t    = threadIdx.x;
    const int lane = t & 63;
    const int w    = t >> 6;
    const int wr = w >> 1, wc = w & 1;
    const int lrow = lane & 15;
    const int lk   = lane >> 4;
    const int bx = blockIdx.x;  // m tile (crit rows)
    const int bz = blockIdx.y;  // batch
    const int h  = blockIdx.z;  // n half (1024 rows)

    // ---- prologue: stage W @0, crit tile @32768 ----
    stage_f32_tile(W, smem, t);
    stage_f32_tile(crit + ((size_t)bz * MDIM + bx * 128) * DDIM, smem + 32768, t);

    // prefetch data tile 0 into registers (hidden under staging + phase 1)
    const float* dbase = data + ((size_t)bz * NDIM + h * 1024) * DDIM;
    float4 ld[8];
    {
        const float* g = dbase;                 // tile 0
        #pragma unroll
        for (int it = 0; it < 4; ++it) {
            const int c = it * 256 + t, row = c >> 4, ks = c & 15;
            const float4* p = (const float4*)(g + row * 128 + ks * 8);
            ld[it * 2] = p[0]; ld[it * 2 + 1] = p[1];
        }
    }

    asm volatile("s_waitcnt lgkmcnt(0)" ::: "memory");
    __builtin_amdgcn_s_barrier();
    __builtin_amdgcn_sched_barrier(0);

    // ---- phase 1: acc1[x][y]: i = wr*64+x*16+lk*4+j, m = wc*64+y*16+lrow ----
    f32x4 acc1[4][4];
    #pragma unroll
    for (int x = 0; x < 4; ++x)
        #pragma unroll
        for (int y = 0; y < 4; ++y)
            acc1[x][y] = (f32x4){0.f, 0.f, 0.f, 0.f};

    #pragma unroll
    for (int ks = 0; ks < 4; ++ks) {
        const int ksl = ks * 4 + lk;
        bf16x8 a1[4], b1[4];
        #pragma unroll
        for (int x = 0; x < 4; ++x) {           // W rows (i)
            const int r = wr * 64 + x * 16 + lrow;
            a1[x] = *(const bf16x8*)(smem + r * 256 + ((ksl ^ (r & 15)) * 16));
        }
        #pragma unroll
        for (int y = 0; y < 4; ++y) {           // crit rows (m)
            const int r = wc * 64 + y * 16 + lrow;
            b1[y] = *(const bf16x8*)(smem + 32768 + r * 256 + ((ksl ^ (r & 15)) * 16));
        }
        #pragma unroll
        for (int x = 0; x < 4; ++x)
            #pragma unroll
            for (int y = 0; y < 4; ++y)
                acc1[x][y] = __builtin_amdgcn_mfma_f32_16x16x32_bf16(
                    a1[x], b1[y], acc1[x][y], 0, 0, 0);
    }

    asm volatile("s_waitcnt lgkmcnt(0)" ::: "memory");
    __builtin_amdgcn_s_barrier();               // all phase-1 LDS reads done
    __builtin_amdgcn_sched_barrier(0);

    // ---- write cw tile (bf16, swizzled) into @0 as the loop's A-tile ----
    {
        const int ks16 = wr * 8 + (lk >> 1);
        const int sub8 = (lk & 1) * 8;
        #pragma unroll
        for (int x = 0; x < 4; ++x)
            #pragma unroll
            for (int y = 0; y < 4; ++y) {
                const int row = wc * 64 + y * 16 + lrow;   // m
                const int ksx = ks16 + x * 2;
                bf16x4 v;
                v[0] = f2bf(acc1[x][y][0]);
                v[1] = f2bf(acc1[x][y][1]);
                v[2] = f2bf(acc1[x][y][2]);
                v[3] = f2bf(acc1[x][y][3]);
                *(bf16x4*)(smem + row * 256 + ((ksx ^ (row & 15)) * 16) + sub8) = v;
            }
    }

    asm volatile("s_waitcnt lgkmcnt(0)" ::: "memory");
    __builtin_amdgcn_s_barrier();               // cw visible to all waves
    __builtin_amdgcn_sched_barrier(0);

    // ---- hoist cw A-fragments to registers (rows m = wr*64+x*16+lrow) ----
    bf16x8 a2r[4][4];
    #pragma unroll
    for (int ks = 0; ks < 4; ++ks) {
        const int ksl = ks * 4 + lk;
        #pragma unroll
        for (int x = 0; x < 4; ++x) {
            const int r = wr * 64 + x * 16 + lrow;
            a2r[x][ks] = *(const bf16x8*)(smem + r * 256 + ((ksl ^ (r & 15)) * 16));
        }
    }

    // ---- main loop: 16 tiles of 64 n-rows, double-buffered @32768/@49152 ----
    for (int tt = 0; tt < 16; ++tt) {
        const int cur = tt & 1;
        char* buf = smem + 32768 + cur * 16384;

        // cvt + ds_write tile tt (regs -> bf16, swizzled); waits its loads
        #pragma unroll
        for (int it = 0; it < 4; ++it) {
            const int c = it * 256 + t, row = c >> 4, ks = c & 15;
            float4 v0 = ld[it * 2], v1 = ld[it * 2 + 1];
            bf16x8 r;
            r[0] = f2bf(v0.x); r[1] = f2bf(v0.y); r[2] = f2bf(v0.z); r[3] = f2bf(v0.w);
            r[4] = f2bf(v1.x); r[5] = f2bf(v1.y); r[6] = f2bf(v1.z); r[7] = f2bf(v1.w);
            *(bf16x8*)(buf + row * 256 + ((ks ^ (row & 15)) * 16)) = r;
        }

        // prefetch tile tt+1 (stays in flight across the barrier)
        if (tt < 15) {
            const float* g = dbase + (size_t)(tt + 1) * 64 * 128;
            #pragma unroll
            for (int it = 0; it < 4; ++it) {
                const int c = it * 256 + t, row = c >> 4, ks = c & 15;
                const float4* p = (const float4*)(g + row * 128 + ks * 8);
                ld[it * 2] = p[0]; ld[it * 2 + 1] = p[1];
            }
        }

        asm volatile("s_waitcnt lgkmcnt(0)" ::: "memory");
        __builtin_amdgcn_s_barrier();           // tile tt visible; loads in flight
        __builtin_amdgcn_sched_barrier(0);

        // ---- compute: out rows n = wc*32+y*16+lrow, cols m = wr*64+x*16+lk*4 ----
        f32x4 acc[4][2];
        #pragma unroll
        for (int x = 0; x < 4; ++x)
            #pragma unroll
            for (int y = 0; y < 2; ++y)
                acc[x][y] = (f32x4){0.f, 0.f, 0.f, 0.f};

        #pragma unroll
        for (int ks = 0; ks < 4; ++ks) {
            const int ksl = ks * 4 + lk;
            bf16x8 b2[2];
            #pragma unroll
            for (int y = 0; y < 2; ++y) {       // data rows (n), 64-row tile
                const int r = wc * 32 + y * 16 + lrow;
                b2[y] = *(const bf16x8*)(buf + r * 256 + ((ksl ^ (r & 15)) * 16));
            }
            #pragma unroll
            for (int x = 0; x < 4; ++x)
                #pragma unroll
                for (int y = 0; y < 2; ++y)
                    acc[x][y] = __builtin_amdgcn_mfma_f32_16x16x32_bf16(
                        a2r[x][ks], b2[y], acc[x][y], 0, 0, 0);
        }

        // ---- stores: out[bz][h*1024 + tt*64 + n][bx*128 + m] ----
        float* ob = out + ((size_t)bz * NDIM + h * 1024 + tt * 64) * MDIM + bx * 128;
        #pragma unroll
        for (int x = 0; x < 4; ++x)
            #pragma unroll
            for (int y = 0; y < 2; ++y) {
                const int n = wc * 32 + y * 16 + lrow;
                const int m = wr * 64 + x * 16 + lk * 4;
                *(f32x4*)(ob + (size_t)n * MDIM + m) = acc[x][y];
            }
        // no trailing barrier needed: next iteration's ds_write targets the
        // OTHER buffer, whose last readers finished before the previous
        // iteration's barrier (program order: compute(tt-1) < barrier(tt)).
    }
}

// ---------------------------------------------------------------------------
extern "C" void kernel_launch(void* const* d_in, const int* in_sizes, int n_in,
                              void* d_out, int out_size, void* d_ws, size_t ws_size,
                              hipStream_t stream) {
    const float* data = (const float*)d_in[0];  // [16,2048,128]
    const float* crit = (const float*)d_in[1];  // [16,2048,128]
    const float* W    = (const float*)d_in[2];  // [1,128,128]
    float* out = (float*)d_out;                 // [16,2048,2048]

    hipLaunchKernelGGL(bd_fused_kernel, dim3(16, 16, 2), dim3(256), 0, stream,
                       data, crit, W, out);
}

// Round 5
// 74.310 us; speedup vs baseline: 1.6197x; 1.2691x over previous
//
#include <hip/hip_runtime.h>
#include <hip/hip_bf16.h>
#include <stdint.h>

#define BATCH 16
#define NDIM  2048
#define MDIM  2048
#define DDIM  128   // LD == RD == 128

using bf16x8 = __attribute__((ext_vector_type(8))) short;
using bf16x4 = __attribute__((ext_vector_type(4))) short;  // 8 B
using f32x4  = __attribute__((ext_vector_type(4))) float;

// async global->LDS, 16B per lane; LDS dest is wave-uniform base + lane*16
#define GLOAD_LDS16(g, l) __builtin_amdgcn_global_load_lds( \
    (const __attribute__((address_space(1))) void*)(g),      \
    (__attribute__((address_space(3))) void*)(l), 16, 0, 0)

__device__ __forceinline__ unsigned short f2bf(float f) {
    unsigned u = __float_as_uint(f);
    u += 0x7fffu + ((u >> 16) & 1u);   // round-to-nearest-even
    return (unsigned short)(u >> 16);
}

// ---------------------------------------------------------------------------
// Stage a 128x128 f32 tile (row stride 128 floats) into LDS as bf16 with the
// XOR-16B-chunk swizzle: logical chunk (row, ks) lands at byte
//   row*256 + (ks ^ (row & 15)) * 16.
// ---------------------------------------------------------------------------
__device__ __forceinline__ void stage_f32_tile(const float* __restrict__ g,
                                               char* lds, int t) {
    #pragma unroll
    for (int it = 0; it < 8; ++it) {
        const int idx = it * 256 + t;           // 16B-bf16-chunk index
        const int row = idx >> 4, ks = idx & 15;
        const float4* p = (const float4*)(g + row * 128 + ks * 8);
        float4 v0 = p[0], v1 = p[1];
        bf16x8 r;
        r[0] = f2bf(v0.x); r[1] = f2bf(v0.y); r[2] = f2bf(v0.z); r[3] = f2bf(v0.w);
        r[4] = f2bf(v1.x); r[5] = f2bf(v1.y); r[6] = f2bf(v1.z); r[7] = f2bf(v1.w);
        *(bf16x8*)(lds + row * 256 + ((ks ^ (row & 15)) * 16)) = r;
    }
}

// ---------------------------------------------------------------------------
// Kernel 1 (prep): per block br (0..255):
//   a) cw tile: cw[br*128+m][i] = sum_j crit[br*128+m][j] * W[i][j]
//      swapped mfma(A=W rows i, B=crit rows m) -> lane holds cw[m][i0..i0+3]
//      -> bf16x4 8-B global stores (R3-verified fragment mapping).
//   b) grid-stride convert data f32 -> bf16 (16 float4 per thread).
// ---------------------------------------------------------------------------
extern "C" __global__ __launch_bounds__(256)
void bd_prep_kernel(const float* __restrict__ data,
                    const float* __restrict__ crit,
                    const float* __restrict__ W,
                    unsigned short* __restrict__ cw,
                    unsigned short* __restrict__ data_b) {
    __shared__ __align__(16) char smem[65536];
    const int t    = threadIdx.x;
    const int lane = t & 63;
    const int w    = t >> 6;
    const int wr = w >> 1, wc = w & 1;
    const int lrow = lane & 15;
    const int lk   = lane >> 4;
    const int br = blockIdx.x;  // 0..255

    stage_f32_tile(W, smem, t);
    stage_f32_tile(crit + (size_t)br * 128 * DDIM, smem + 32768, t);
    __syncthreads();

    f32x4 acc1[4][4];
    #pragma unroll
    for (int x = 0; x < 4; ++x)
        #pragma unroll
        for (int y = 0; y < 4; ++y)
            acc1[x][y] = (f32x4){0.f, 0.f, 0.f, 0.f};

    #pragma unroll
    for (int ks = 0; ks < 4; ++ks) {
        const int ksl = ks * 4 + lk;
        bf16x8 a1[4], b1[4];
        #pragma unroll
        for (int x = 0; x < 4; ++x) {           // W rows (i)
            const int r = wr * 64 + x * 16 + lrow;
            a1[x] = *(const bf16x8*)(smem + r * 256 + ((ksl ^ (r & 15)) * 16));
        }
        #pragma unroll
        for (int y = 0; y < 4; ++y) {           // crit rows (m)
            const int r = wc * 64 + y * 16 + lrow;
            b1[y] = *(const bf16x8*)(smem + 32768 + r * 256 + ((ksl ^ (r & 15)) * 16));
        }
        #pragma unroll
        for (int x = 0; x < 4; ++x)
            #pragma unroll
            for (int y = 0; y < 4; ++y)
                acc1[x][y] = __builtin_amdgcn_mfma_f32_16x16x32_bf16(
                    a1[x], b1[y], acc1[x][y], 0, 0, 0);
    }

    // cw[m][i]: m = wc*64+y*16+lrow, i = wr*64+x*16+lk*4+j -> 8-B stores
    unsigned short* Cb = cw + (size_t)br * 128 * 128;
    #pragma unroll
    for (int x = 0; x < 4; ++x)
        #pragma unroll
        for (int y = 0; y < 4; ++y) {
            bf16x4 v;
            v[0] = f2bf(acc1[x][y][0]);
            v[1] = f2bf(acc1[x][y][1]);
            v[2] = f2bf(acc1[x][y][2]);
            v[3] = f2bf(acc1[x][y][3]);
            *(bf16x4*)(Cb + (wc * 64 + y * 16 + lrow) * 128 +
                       wr * 64 + x * 16 + lk * 4) = v;
        }

    // b) convert data f32 -> bf16, grid-stride over 1M float4s
    const float4*  s = (const float4*)data;
    ushort4*       d = (ushort4*)data_b;
    const int gtid = br * 256 + t;              // 65536 threads
    #pragma unroll 4
    for (int i = gtid; i < (BATCH * NDIM * DDIM / 4); i += 65536) {
        float4 v = s[i];
        ushort4 r;
        r.x = f2bf(v.x); r.y = f2bf(v.y); r.z = f2bf(v.z); r.w = f2bf(v.w);
        d[i] = r;
    }
}

// ---------------------------------------------------------------------------
// Kernel 2 (main): block (bx, ny, bz) computes out tile 64n x 128m:
//   out[bz][ny*64+n][bx*128+m] = sum_i data[bz][n'][i] * cw[bz][m'][i]
// A = cw tile (128 rows m, 32 KB), B = data tile (64 rows n, 16 KB), both
// bf16-swizzled via global_load_lds (pre-swizzled source kseg).
// Swapped mfma(A=cw rows, B=data rows) -> lane holds out[n][m0..m0+3]
// -> float4 stores. Stores interleaved per m-fragment.
// LDS 48 KB -> 3 blocks/CU.
// ---------------------------------------------------------------------------
extern "C" __global__ __launch_bounds__(256, 3)
void bd_main_kernel(const unsigned short* __restrict__ data_b,
                    const unsigned short* __restrict__ cw,
                    float* __restrict__ out) {
    __shared__ __align__(16) char smem[49152];
    const int t    = threadIdx.x;
    const int lane = t & 63;
    const int w    = t >> 6;
    const int wr = w >> 1, wc = w & 1;
    const int lrow = lane & 15;
    const int lk   = lane >> 4;
    const int bx = blockIdx.x;  // m tile (128)
    const int ny = blockIdx.y;  // n tile (64)
    const int bz = blockIdx.z;  // batch

    // ---- stage A (cw, 128 rows, 2048 chunks) and B (data, 64 rows, 1024) ----
    const char* Ag = (const char*)cw +     ((size_t)bz * MDIM + bx * 128) * 256;
    const char* Bg = (const char*)data_b + ((size_t)bz * NDIM + ny * 64) * 256;
    #pragma unroll
    for (int it = 0; it < 8; ++it) {
        const int cb = it * 256 + w * 64;       // wave-uniform chunk base
        const int c  = cb + lane;
        const int row = c >> 4, ks = c & 15;
        const int ksrc = ks ^ (row & 15);
        GLOAD_LDS16(Ag + (size_t)row * 256 + ksrc * 16, smem + cb * 16);
    }
    #pragma unroll
    for (int it = 0; it < 4; ++it) {
        const int cb = it * 256 + w * 64;
        const int c  = cb + lane;
        const int row = c >> 4, ks = c & 15;
        const int ksrc = ks ^ (row & 15);
        GLOAD_LDS16(Bg + (size_t)row * 256 + ksrc * 16, smem + 32768 + cb * 16);
    }
    __syncthreads();

    // ---- hoist B fragments (data rows n = wc*32 + y*16 + lrow) ----
    bf16x8 b2[2][4];
    #pragma unroll
    for (int ks = 0; ks < 4; ++ks) {
        const int ksl = ks * 4 + lk;
        #pragma unroll
        for (int y = 0; y < 2; ++y) {
            const int r = wc * 32 + y * 16 + lrow;
            b2[y][ks] = *(const bf16x8*)(smem + 32768 + r * 256 +
                                         ((ksl ^ (r & 15)) * 16));
        }
    }

    // ---- per m-fragment: 4 ds_read + 8 MFMA + 2 stores (interleaved) ----
    float* ob = out + ((size_t)bz * NDIM + ny * 64) * MDIM + bx * 128;
    #pragma unroll
    for (int x = 0; x < 4; ++x) {
        f32x4 acc[2];
        acc[0] = (f32x4){0.f, 0.f, 0.f, 0.f};
        acc[1] = (f32x4){0.f, 0.f, 0.f, 0.f};
        const int r = wr * 64 + x * 16 + lrow;  // cw row (m)
        #pragma unroll
        for (int ks = 0; ks < 4; ++ks) {
            const int ksl = ks * 4 + lk;
            bf16x8 a2 = *(const bf16x8*)(smem + r * 256 + ((ksl ^ (r & 15)) * 16));
            #pragma unroll
            for (int y = 0; y < 2; ++y)
                acc[y] = __builtin_amdgcn_mfma_f32_16x16x32_bf16(
                    a2, b2[y][ks], acc[y], 0, 0, 0);
        }
        const int m = wr * 64 + x * 16 + lk * 4;
        #pragma unroll
        for (int y = 0; y < 2; ++y) {
            const int n = wc * 32 + y * 16 + lrow;
            *(f32x4*)(ob + (size_t)n * MDIM + m) = acc[y];
        }
    }
}

// ---------------------------------------------------------------------------
extern "C" void kernel_launch(void* const* d_in, const int* in_sizes, int n_in,
                              void* d_out, int out_size, void* d_ws, size_t ws_size,
                              hipStream_t stream) {
    const float* data = (const float*)d_in[0];  // [16,2048,128]
    const float* crit = (const float*)d_in[1];  // [16,2048,128]
    const float* W    = (const float*)d_in[2];  // [1,128,128]
    float* out = (float*)d_out;                 // [16,2048,2048]

    char* ws = (char*)d_ws;
    unsigned short* cw     = (unsigned short*)ws;              // 8 MB bf16
    unsigned short* data_b = (unsigned short*)(ws + 8388608);  // 8 MB bf16

    hipLaunchKernelGGL(bd_prep_kernel, dim3(256), dim3(256), 0, stream,
                       data, crit, W, cw, data_b);
    hipLaunchKernelGGL(bd_main_kernel, dim3(16, 32, 16), dim3(256), 0, stream,
                       data_b, cw, out);
}

// Round 6
// 70.867 us; speedup vs baseline: 1.6984x; 1.0486x over previous
//
#include <hip/hip_runtime.h>
#include <hip/hip_bf16.h>
#include <stdint.h>

#define BATCH 16
#define NDIM  2048
#define MDIM  2048
#define DDIM  128   // LD == RD == 128

using bf16x8 = __attribute__((ext_vector_type(8))) short;
using bf16x4 = __attribute__((ext_vector_type(4))) short;  // 8 B
using f32x4  = __attribute__((ext_vector_type(4))) float;

// async global->LDS, 16B per lane; LDS dest is wave-uniform base + lane*16
#define GLOAD_LDS16(g, l) __builtin_amdgcn_global_load_lds( \
    (const __attribute__((address_space(1))) void*)(g),      \
    (__attribute__((address_space(3))) void*)(l), 16, 0, 0)

__device__ __forceinline__ unsigned short f2bf(float f) {
    unsigned u = __float_as_uint(f);
    u += 0x7fffu + ((u >> 16) & 1u);   // round-to-nearest-even
    return (unsigned short)(u >> 16);
}

// ---------------------------------------------------------------------------
// Stage a 128x128 f32 tile (row stride 128 floats) into LDS as bf16 with the
// XOR-16B-chunk swizzle: logical chunk (row, ks) lands at byte
//   row*256 + (ks ^ (row & 15)) * 16.
// ---------------------------------------------------------------------------
__device__ __forceinline__ void stage_f32_tile(const float* __restrict__ g,
                                               char* lds, int t) {
    #pragma unroll
    for (int it = 0; it < 8; ++it) {
        const int idx = it * 256 + t;           // 16B-bf16-chunk index
        const int row = idx >> 4, ks = idx & 15;
        const float4* p = (const float4*)(g + row * 128 + ks * 8);
        float4 v0 = p[0], v1 = p[1];
        bf16x8 r;
        r[0] = f2bf(v0.x); r[1] = f2bf(v0.y); r[2] = f2bf(v0.z); r[3] = f2bf(v0.w);
        r[4] = f2bf(v1.x); r[5] = f2bf(v1.y); r[6] = f2bf(v1.z); r[7] = f2bf(v1.w);
        *(bf16x8*)(lds + row * 256 + ((ks ^ (row & 15)) * 16)) = r;
    }
}

// ---------------------------------------------------------------------------
// Kernel 1 (prep): per block br (0..255):
//   a) cw tile: cw[br*128+m][i] = sum_j crit[br*128+m][j] * W[i][j]
//      swapped mfma(A=W rows i, B=crit rows m) -> lane holds cw[m][i0..i0+3]
//      -> bf16x4 8-B global stores (R3-verified fragment mapping).
//   b) grid-stride convert data f32 -> bf16.
// ---------------------------------------------------------------------------
extern "C" __global__ __launch_bounds__(256)
void bd_prep_kernel(const float* __restrict__ data,
                    const float* __restrict__ crit,
                    const float* __restrict__ W,
                    unsigned short* __restrict__ cw,
                    unsigned short* __restrict__ data_b) {
    __shared__ __align__(16) char smem[65536];
    const int t    = threadIdx.x;
    const int lane = t & 63;
    const int w    = t >> 6;
    const int wr = w >> 1, wc = w & 1;
    const int lrow = lane & 15;
    const int lk   = lane >> 4;
    const int br = blockIdx.x;  // 0..255

    stage_f32_tile(W, smem, t);
    stage_f32_tile(crit + (size_t)br * 128 * DDIM, smem + 32768, t);
    __syncthreads();

    f32x4 acc1[4][4];
    #pragma unroll
    for (int x = 0; x < 4; ++x)
        #pragma unroll
        for (int y = 0; y < 4; ++y)
            acc1[x][y] = (f32x4){0.f, 0.f, 0.f, 0.f};

    #pragma unroll
    for (int ks = 0; ks < 4; ++ks) {
        const int ksl = ks * 4 + lk;
        bf16x8 a1[4], b1[4];
        #pragma unroll
        for (int x = 0; x < 4; ++x) {           // W rows (i)
            const int r = wr * 64 + x * 16 + lrow;
            a1[x] = *(const bf16x8*)(smem + r * 256 + ((ksl ^ (r & 15)) * 16));
        }
        #pragma unroll
        for (int y = 0; y < 4; ++y) {           // crit rows (m)
            const int r = wc * 64 + y * 16 + lrow;
            b1[y] = *(const bf16x8*)(smem + 32768 + r * 256 + ((ksl ^ (r & 15)) * 16));
        }
        #pragma unroll
        for (int x = 0; x < 4; ++x)
            #pragma unroll
            for (int y = 0; y < 4; ++y)
                acc1[x][y] = __builtin_amdgcn_mfma_f32_16x16x32_bf16(
                    a1[x], b1[y], acc1[x][y], 0, 0, 0);
    }

    // cw[m][i]: m = wc*64+y*16+lrow, i = wr*64+x*16+lk*4+j -> 8-B stores
    unsigned short* Cb = cw + (size_t)br * 128 * 128;
    #pragma unroll
    for (int x = 0; x < 4; ++x)
        #pragma unroll
        for (int y = 0; y < 4; ++y) {
            bf16x4 v;
            v[0] = f2bf(acc1[x][y][0]);
            v[1] = f2bf(acc1[x][y][1]);
            v[2] = f2bf(acc1[x][y][2]);
            v[3] = f2bf(acc1[x][y][3]);
            *(bf16x4*)(Cb + (wc * 64 + y * 16 + lrow) * 128 +
                       wr * 64 + x * 16 + lk * 4) = v;
        }

    // b) convert data f32 -> bf16, grid-stride over 1M float4s
    const float4*  s = (const float4*)data;
    ushort4*       d = (ushort4*)data_b;
    const int gtid = br * 256 + t;              // 65536 threads
    #pragma unroll 4
    for (int i = gtid; i < (BATCH * NDIM * DDIM / 4); i += 65536) {
        float4 v = s[i];
        ushort4 r;
        r.x = f2bf(v.x); r.y = f2bf(v.y); r.z = f2bf(v.z); r.w = f2bf(v.w);
        d[i] = r;
    }
}

// ---------------------------------------------------------------------------
// Kernel 2 (main): block (bx, ny, bz) computes out tile 64n x 128m:
//   out[bz][ny*64+n][bx*128+m] = sum_i data[bz][n'][i] * cw[bz][m'][i]
// A = cw tile (128 rows m, 32 KB), B = data tile (64 rows n, 16 KB), via
// global_load_lds with pre-swizzled source kseg. Swapped mfma(A=cw, B=data)
// -> lane holds out[n][m0..m0+3]. Epilogue: LDS-transpose the 64x128 f32
// tile (reusing the staging LDS) then fully-coalesced nontemporal float4
// stores (1 KB contiguous per wave instruction).
// LDS 48 KB -> 3 blocks/CU.
// ---------------------------------------------------------------------------
extern "C" __global__ __launch_bounds__(256, 3)
void bd_main_kernel(const unsigned short* __restrict__ data_b,
                    const unsigned short* __restrict__ cw,
                    float* __restrict__ out) {
    __shared__ __align__(16) char smem[49152];
    const int t    = threadIdx.x;
    const int lane = t & 63;
    const int w    = t >> 6;
    const int wr = w >> 1, wc = w & 1;
    const int lrow = lane & 15;
    const int lk   = lane >> 4;
    const int bx = blockIdx.x;  // m tile (128)
    const int ny = blockIdx.y;  // n tile (64)
    const int bz = blockIdx.z;  // batch

    // ---- stage A (cw, 128 rows, 2048 chunks) and B (data, 64 rows, 1024) ----
    const char* Ag = (const char*)cw +     ((size_t)bz * MDIM + bx * 128) * 256;
    const char* Bg = (const char*)data_b + ((size_t)bz * NDIM + ny * 64) * 256;
    #pragma unroll
    for (int it = 0; it < 8; ++it) {
        const int cb = it * 256 + w * 64;       // wave-uniform chunk base
        const int c  = cb + lane;
        const int row = c >> 4, ks = c & 15;
        const int ksrc = ks ^ (row & 15);
        GLOAD_LDS16(Ag + (size_t)row * 256 + ksrc * 16, smem + cb * 16);
    }
    #pragma unroll
    for (int it = 0; it < 4; ++it) {
        const int cb = it * 256 + w * 64;
        const int c  = cb + lane;
        const int row = c >> 4, ks = c & 15;
        const int ksrc = ks ^ (row & 15);
        GLOAD_LDS16(Bg + (size_t)row * 256 + ksrc * 16, smem + 32768 + cb * 16);
    }
    __syncthreads();

    // ---- hoist B fragments (data rows n = wc*32 + y*16 + lrow) ----
    bf16x8 b2[2][4];
    #pragma unroll
    for (int ks = 0; ks < 4; ++ks) {
        const int ksl = ks * 4 + lk;
        #pragma unroll
        for (int y = 0; y < 2; ++y) {
            const int r = wc * 32 + y * 16 + lrow;
            b2[y][ks] = *(const bf16x8*)(smem + 32768 + r * 256 +
                                         ((ksl ^ (r & 15)) * 16));
        }
    }

    // ---- MFMA: acc[x][y], n = wc*32+y*16+lrow, m = wr*64+x*16+lk*4+j ----
    f32x4 acc[4][2];
    #pragma unroll
    for (int x = 0; x < 4; ++x) {
        acc[x][0] = (f32x4){0.f, 0.f, 0.f, 0.f};
        acc[x][1] = (f32x4){0.f, 0.f, 0.f, 0.f};
        const int r = wr * 64 + x * 16 + lrow;  // cw row (m)
        #pragma unroll
        for (int ks = 0; ks < 4; ++ks) {
            const int ksl = ks * 4 + lk;
            bf16x8 a2 = *(const bf16x8*)(smem + r * 256 + ((ksl ^ (r & 15)) * 16));
            #pragma unroll
            for (int y = 0; y < 2; ++y)
                acc[x][y] = __builtin_amdgcn_mfma_f32_16x16x32_bf16(
                    a2, b2[y][ks], acc[x][y], 0, 0, 0);
        }
    }
    __syncthreads();    // all LDS reads done; safe to overwrite with out tile

    // ---- epilogue stage 1: acc -> LDS [64][128] f32, XOR-swizzled ----
    // byte addr = n*512 + ((m*4) ^ ((n&7)<<4)); 16-B granular, 2-way max.
    #pragma unroll
    for (int x = 0; x < 4; ++x)
        #pragma unroll
        for (int y = 0; y < 2; ++y) {
            const int n = wc * 32 + y * 16 + lrow;
            const int m = wr * 64 + x * 16 + lk * 4;
            *(f32x4*)(smem + n * 512 + ((m * 4) ^ ((n & 7) << 4))) = acc[x][y];
        }
    __syncthreads();

    // ---- epilogue stage 2: linear re-read + coalesced nontemporal stores ----
    // thread t, iter i: float4 index idx = i*256+t; row = idx>>5, c4 = idx&31.
    // Each wave instruction writes 2 rows x 512 B contiguous.
    float* ob = out + ((size_t)bz * NDIM + ny * 64) * MDIM + bx * 128;
    #pragma unroll
    for (int i = 0; i < 8; ++i) {
        const int idx = i * 256 + t;
        const int row = idx >> 5, c4 = idx & 31;
        f32x4 v = *(const f32x4*)(smem + row * 512 + ((c4 * 16) ^ ((row & 7) << 4)));
        __builtin_nontemporal_store(v, (f32x4*)(ob + (size_t)row * MDIM + c4 * 4));
    }
}

// ---------------------------------------------------------------------------
extern "C" void kernel_launch(void* const* d_in, const int* in_sizes, int n_in,
                              void* d_out, int out_size, void* d_ws, size_t ws_size,
                              hipStream_t stream) {
    const float* data = (const float*)d_in[0];  // [16,2048,128]
    const float* crit = (const float*)d_in[1];  // [16,2048,128]
    const float* W    = (const float*)d_in[2];  // [1,128,128]
    float* out = (float*)d_out;                 // [16,2048,2048]

    char* ws = (char*)d_ws;
    unsigned short* cw     = (unsigned short*)ws;              // 8 MB bf16
    unsigned short* data_b = (unsigned short*)(ws + 8388608);  // 8 MB bf16

    hipLaunchKernelGGL(bd_prep_kernel, dim3(256), dim3(256), 0, stream,
                       data, crit, W, cw, data_b);
    hipLaunchKernelGGL(bd_main_kernel, dim3(16, 32, 16), dim3(256), 0, stream,
                       data_b, cw, out);
}